// Round 13
// baseline (9050.229 us; speedup 1.0000x reference)
//
#include <hip/hip_runtime.h>

#define Hd 1024
#define Sd 4096
#define G4 4096   // 4*H

typedef __attribute__((ext_vector_type(8))) short    bf16x8;
typedef __attribute__((ext_vector_type(8))) unsigned short u16x8;
typedef __attribute__((ext_vector_type(4))) unsigned short u16x4;
typedef __attribute__((ext_vector_type(4))) unsigned u32x4;
typedef __attribute__((ext_vector_type(4))) float    f32x4;

// ---- ws layout (bytes) ----
#define WS_WHH_F 0u                 // 4096*1024*2 = 8388608
#define WS_WIH_F 8388608u           // 8388608
#define WS_EMB_F 16777216u          // 8388608 (dead after gemm_k; hrec reuses its head)
#define WS_HREC  16777216u          // 2 buffers x 256 chunks x 16B = 8192
#define WS_XG    25165824u          // 4096*4096*2 = 33554432
#define WS_BIAS  58720256u          // 4096*4 = 16384
                                    // NOTE: t=4095's xg t+1 prefetch reads the bias
                                    // region (in-bounds of d_ws, values unused).

__device__ __forceinline__ float b2f(unsigned short u) {
    return __uint_as_float(((unsigned)u) << 16);
}
__device__ __forceinline__ unsigned short f2b(float f) {
    unsigned u = __float_as_uint(f);
    unsigned r = u + 0x7fffu + ((u >> 16) & 1u);   // RNE
    return (unsigned short)(r >> 16);
}
__device__ __forceinline__ float sigmoid_fast(float x) {
    return 1.f / (1.f + __expf(-x));   // inf-safe at both ends
}
__device__ __forceinline__ float tanh_fast(float x) {
    float e = __expf(2.f * fabsf(x));  // inf-safe: 2/(inf+1)=0 -> +-1
    return copysignf(1.f - 2.f / (e + 1.f), x);
}

// Pack a [R x 1024] f32 matrix (optionally row-gathered by idx) into MFMA
// A-fragment order: chunk(rb,kb) = 64 lanes x 8 bf16,
// elem(l,j) = src[rb*16 + (l&15)][kb*32 + (l>>4)*8 + j]
__global__ void pack_frag(const float* __restrict__ src, const int* __restrict__ idx,
                          unsigned short* __restrict__ dst) {
    const int rb = blockIdx.x;       // 0..255
    const int kb = blockIdx.y;       // 0..31
    const int l  = threadIdx.x;      // 0..63
    int row = rb * 16 + (l & 15);
    if (idx) row = idx[row];
    const float* s = src + (size_t)row * Hd + kb * 32 + ((l >> 4) & 3) * 8;
    float4 f0 = *(const float4*)s;
    float4 f1 = *(const float4*)(s + 4);
    u16x8 v;
    v[0]=f2b(f0.x); v[1]=f2b(f0.y); v[2]=f2b(f0.z); v[3]=f2b(f0.w);
    v[4]=f2b(f1.x); v[5]=f2b(f1.y); v[6]=f2b(f1.z); v[7]=f2b(f1.w);
    *(u16x8*)(dst + ((size_t)(rb * 32 + kb) * 64 + l) * 8) = v;
}

__global__ void init_k(const float* __restrict__ bih, const float* __restrict__ bhh,
                       float* __restrict__ bias) {
    const int i = blockIdx.x * 256 + threadIdx.x;   // 0..4095
    bias[i] = bih[i] + bhh[i];
}

// zero BOTH hrec buffers (tags 0; garbage could alias a future tag).
__global__ void zero_hrec_k(unsigned* __restrict__ hrec) {
    hrec[blockIdx.x * 256 + threadIdx.x] = 0u;      // 2048 dwords
}

// xg[s][n] = sum_k embs[s][k]*W_ih[n][k] + bias[n], bf16 out.
__global__ __launch_bounds__(256, 2)
void gemm_k(const unsigned short* __restrict__ Af, const unsigned short* __restrict__ Bf,
            const float* __restrict__ bias, unsigned short* __restrict__ xg) {
    const int w = threadIdx.x >> 6, l = threadIdx.x & 63;
    const int wid = blockIdx.x * 4 + w;      // 0..4095
    const int mg = wid >> 6;                 // 0..63
    const int ng = wid & 63;                 // 0..63

    f32x4 acc[4][4] = {};
    for (int kb = 0; kb < 32; ++kb) {
        bf16x8 a[4], b[4];
#pragma unroll
        for (int mi = 0; mi < 4; ++mi)
            a[mi] = *(const bf16x8*)(Af + (((size_t)(mg * 4 + mi) * 32 + kb) * 64 + l) * 8);
#pragma unroll
        for (int ni = 0; ni < 4; ++ni)
            b[ni] = *(const bf16x8*)(Bf + (((size_t)(ng * 4 + ni) * 32 + kb) * 64 + l) * 8);
#pragma unroll
        for (int mi = 0; mi < 4; ++mi)
#pragma unroll
            for (int ni = 0; ni < 4; ++ni)
                acc[mi][ni] = __builtin_amdgcn_mfma_f32_16x16x32_bf16(a[mi], b[ni], acc[mi][ni], 0, 0, 0);
    }
    const int r4 = (l >> 4) * 4, c = l & 15;
#pragma unroll
    for (int ni = 0; ni < 4; ++ni) {
        const int col = ng * 64 + ni * 16 + c;
        const float bv = bias[col];
#pragma unroll
        for (int mi = 0; mi < 4; ++mi) {
            const int rowb = mg * 64 + mi * 16 + r4;
#pragma unroll
            for (int i = 0; i < 4; ++i)
                xg[(size_t)(rowb + i) * G4 + col] = f2b(acc[mi][ni][i] + bv);
        }
    }
}

// Persistent LSTM scan. 32 WGs x 512 thr (8 waves). WG r owns h[r*32, r*32+32).
// Wave w: gate w>>1, rows r*32 + (w&1)*16 .. +16 (one 16-row block, 32 MFMAs,
// W_hh in 128 VGPRs -> no spill under launch_bounds(512,2)).
// Transport (r4/r11-proven): 256 dual-tagged 16B chunks at LLC scope (sc0 sc1);
// threads 0..255 poll chunk tid with the drained single-sample loop, with an
// s_sleep(6) phase offset (r13: tuned down from 12) so sample 1 lands fresh.
// Waves 4-7 skip polling (wait at B1). Cell redundant in all 8 waves; wave w
// publishes chunk role*8+w. No dangling VMEM anywhere.
__global__ __launch_bounds__(512, 2)
void scan_k(const unsigned short* __restrict__ Wf, const unsigned short* __restrict__ xg,
            unsigned* __restrict__ hrec, float* __restrict__ out) {
    __shared__ unsigned h_sw[512];        // full h as 512 dwords (1024 bf16)
    __shared__ float g_lds[128];          // [gate 0..3][lh 0..31]

    const int role = blockIdx.x;          // 0..31
    const int tid  = threadIdx.x;         // 0..511
    const int w = tid >> 6, l = tid & 63;
    const int gate = w >> 1, half = w & 1;
    const int rb = (gate << 6) + (role << 1) + half;   // row-block index in W packing

    bf16x8 wfrag[32];                     // 128 VGPRs of W_hh (compiler-resident)
#pragma unroll
    for (int kb = 0; kb < 32; ++kb)
        wfrag[kb] = *(const bf16x8*)(Wf + (((size_t)rb * 32 + kb) * 64 + l) * 8);

    float c_reg = 0.f;                    // lanes l<32: cell state (redundant per wave)
    const int hoff = ((l >> 4) & 3) * 8;  // bf16 offset within each 32-chunk of h
    const int r0 = (l >> 4) << 2;
    const unsigned short* h_ss = (const unsigned short*)h_sw;
    const int xbase = (gate << 10) + (role << 5) + (half << 4) + r0;

    // xg t=0 prefetch (plain loads; compiler-managed waits)
    u16x4 xv = {0, 0, 0, 0};
    if ((l & 15) == 0)
        xv = *(const u16x4*)(xg + xbase);

    for (int t = 0; t < Sd; ++t) {
        const unsigned tt = (unsigned)t;

        // ---- waves 0-3: poll own chunk (drained, phase-offset), stage to LDS ----
        if (tid < 256) {
            const unsigned* gp = hrec + (t & 1) * 1024 + tid * 4;
            u32x4 pA;
            __builtin_amdgcn_s_sleep(6);    // ~384cy phase offset (r13: tuned from 768)
            int guard = 0;
            while (true) {
                asm volatile("global_load_dwordx4 %0, %1, off sc0 sc1\n\ts_waitcnt vmcnt(0)"
                             : "=v"(pA) : "v"(gp) : "memory");
                __builtin_amdgcn_sched_barrier(0);
                if (!__any((pA[1] != tt) | (pA[3] != tt))) break;
                if (++guard > 65536) break;   // bounded: wrong, never hang
                __builtin_amdgcn_s_sleep(1);
            }
            h_sw[tid * 2]     = pA[0];
            h_sw[tid * 2 + 1] = pA[2];
            asm volatile("s_waitcnt lgkmcnt(0)" ::: "memory");
        }
        __builtin_amdgcn_s_barrier();                          // B1
        __builtin_amdgcn_sched_barrier(0);

        // ---- 32 MFMAs: 4 interleaved 8-deep chains ----
        f32x4 ac0 = {0,0,0,0}, ac1 = {0,0,0,0}, ac2 = {0,0,0,0}, ac3 = {0,0,0,0};
#pragma unroll
        for (int kb = 0; kb < 32; kb += 4) {
            bf16x8 h0 = *(const bf16x8*)(h_ss + (kb + 0) * 32 + hoff);
            bf16x8 h1 = *(const bf16x8*)(h_ss + (kb + 1) * 32 + hoff);
            bf16x8 h2 = *(const bf16x8*)(h_ss + (kb + 2) * 32 + hoff);
            bf16x8 h3 = *(const bf16x8*)(h_ss + (kb + 3) * 32 + hoff);
            ac0 = __builtin_amdgcn_mfma_f32_16x16x32_bf16(wfrag[kb + 0], h0, ac0, 0, 0, 0);
            ac1 = __builtin_amdgcn_mfma_f32_16x16x32_bf16(wfrag[kb + 1], h1, ac1, 0, 0, 0);
            ac2 = __builtin_amdgcn_mfma_f32_16x16x32_bf16(wfrag[kb + 2], h2, ac2, 0, 0, 0);
            ac3 = __builtin_amdgcn_mfma_f32_16x16x32_bf16(wfrag[kb + 3], h3, ac3, 0, 0, 0);
        }
        f32x4 acc = (ac0 + ac1) + (ac2 + ac3);

        if ((l & 15) == 0) {   // lanes 0,16,32,48 hold rows r0..r0+3 (col 0)
#pragma unroll
            for (int i = 0; i < 4; ++i)
                g_lds[(gate << 5) + (half << 4) + r0 + i] = acc[i] + b2f(xv[i]);
        }
        asm volatile("s_waitcnt lgkmcnt(0)" ::: "memory");
        __builtin_amdgcn_s_barrier();                          // B2
        __builtin_amdgcn_sched_barrier(0);

        // ---- LSTM cell, redundant in all 8 waves (lanes l<32) ----
        float h = 0.f; unsigned short hb = 0;
        if (l < 32) {
            float iv = sigmoid_fast(g_lds[l]);
            float fv = sigmoid_fast(g_lds[32 + l]);
            float gv = tanh_fast(g_lds[64 + l]);
            float ov = sigmoid_fast(g_lds[96 + l]);
            float c = fv * c_reg + iv * gv;
            c_reg = c;
            h = ov * tanh_fast(c);
            hb = f2b(h);
        }
        // wave w publishes chunk role*8+w = {h[4w..4w+1], tag, h[4w+2..4w+3], tag}
        unsigned p   = (unsigned)hb | ((unsigned)__shfl_xor((int)(unsigned)hb, 1, 64) << 16);
        unsigned p2v = (unsigned)__shfl((int)p, (l & ~3) + 2, 64);
        if (l == (w << 2)) {
            const unsigned tag = tt + 1u;
            u32x4 val = {p, tag, p2v, tag};
            unsigned* dst = hrec + ((t + 1) & 1) * 1024 + ((role << 3) + w) * 4;
            asm volatile("global_store_dwordx4 %0, %1, off sc0 sc1"
                         :: "v"(dst), "v"(val) : "memory");
        }
        // out[] (wave 0 only) and next-step xg AFTER the publish
        if (w == 0 && l < 32) {
            out[(size_t)Hd + (size_t)t * Hd + (role << 5) + l] = h;   // outs[t]
            if (t == Sd - 1) out[(role << 5) + l] = h;                // final h
        }
        if ((l & 15) == 0)
            xv = *(const u16x4*)(xg + (size_t)(t + 1) * G4 + xbase);
        // per-wave FIFO: the compiler's wait for xv-use (and waves 0-3's poll
        // drains) retire the publish store before the same wave's next publish.
    }
}

extern "C" void kernel_launch(void* const* d_in, const int* in_sizes, int n_in,
                              void* d_out, int out_size, void* d_ws, size_t ws_size,
                              hipStream_t stream) {
    (void)in_sizes; (void)n_in; (void)out_size; (void)ws_size;
    const int*   x   = (const int*)  d_in[0];
    const float* emb = (const float*)d_in[1];
    const float* Wih = (const float*)d_in[2];
    const float* Whh = (const float*)d_in[3];
    const float* bih = (const float*)d_in[4];
    const float* bhh = (const float*)d_in[5];
    float* out = (float*)d_out;

    char* ws = (char*)d_ws;
    unsigned short* whh_f = (unsigned short*)(ws + WS_WHH_F);
    unsigned short* wih_f = (unsigned short*)(ws + WS_WIH_F);
    unsigned short* emb_f = (unsigned short*)(ws + WS_EMB_F);
    unsigned short* xgp   = (unsigned short*)(ws + WS_XG);
    float*          bias  = (float*)        (ws + WS_BIAS);
    unsigned*       hrec  = (unsigned*)      (ws + WS_HREC);

    init_k     <<<16, 256, 0, stream>>>(bih, bhh, bias);
    pack_frag  <<<dim3(256, 32), 64, 0, stream>>>(Whh, nullptr, whh_f);
    pack_frag  <<<dim3(256, 32), 64, 0, stream>>>(Wih, nullptr, wih_f);
    pack_frag  <<<dim3(256, 32), 64, 0, stream>>>(emb, x,       emb_f);
    gemm_k     <<<1024, 256, 0, stream>>>(emb_f, wih_f, bias, xgp);
    zero_hrec_k<<<8, 256, 0, stream>>>(hrec);          // after gemm: hrec aliases emb_f
    scan_k     <<<32, 512, 0, stream>>>(whh_f, xgp, hrec, out);
}

// Round 14
// 8560.101 us; speedup vs baseline: 1.0573x; 1.0573x over previous
//
#include <hip/hip_runtime.h>

#define Hd 1024
#define Sd 4096
#define G4 4096   // 4*H

typedef __attribute__((ext_vector_type(8))) short    bf16x8;
typedef __attribute__((ext_vector_type(8))) unsigned short u16x8;
typedef __attribute__((ext_vector_type(4))) unsigned short u16x4;
typedef __attribute__((ext_vector_type(4))) unsigned u32x4;
typedef __attribute__((ext_vector_type(4))) float    f32x4;

// ---- ws layout (bytes) ----
#define WS_WHH_F 0u                 // 4096*1024*2 = 8388608
#define WS_WIH_F 8388608u           // 8388608
#define WS_EMB_F 16777216u          // 8388608 (dead after gemm_k; hrec reuses its head)
#define WS_HREC  16777216u          // 2 buffers x 256 chunks x 16B = 8192
#define WS_XG    25165824u          // 4096*4096*2 = 33554432
#define WS_BIAS  58720256u          // 4096*4 = 16384
                                    // NOTE: t=4095's xg t+1 prefetch reads the bias
                                    // region (in-bounds of d_ws, values unused).

__device__ __forceinline__ float b2f(unsigned short u) {
    return __uint_as_float(((unsigned)u) << 16);
}
__device__ __forceinline__ unsigned short f2b(float f) {
    unsigned u = __float_as_uint(f);
    unsigned r = u + 0x7fffu + ((u >> 16) & 1u);   // RNE
    return (unsigned short)(r >> 16);
}
__device__ __forceinline__ float sigmoid_fast(float x) {
    return 1.f / (1.f + __expf(-x));   // inf-safe at both ends
}
__device__ __forceinline__ float tanh_fast(float x) {
    float e = __expf(2.f * fabsf(x));  // inf-safe: 2/(inf+1)=0 -> +-1
    return copysignf(1.f - 2.f / (e + 1.f), x);
}

// Pack a [R x 1024] f32 matrix (optionally row-gathered by idx) into MFMA
// A-fragment order: chunk(rb,kb) = 64 lanes x 8 bf16,
// elem(l,j) = src[rb*16 + (l&15)][kb*32 + (l>>4)*8 + j]
__global__ void pack_frag(const float* __restrict__ src, const int* __restrict__ idx,
                          unsigned short* __restrict__ dst) {
    const int rb = blockIdx.x;       // 0..255
    const int kb = blockIdx.y;       // 0..31
    const int l  = threadIdx.x;      // 0..63
    int row = rb * 16 + (l & 15);
    if (idx) row = idx[row];
    const float* s = src + (size_t)row * Hd + kb * 32 + ((l >> 4) & 3) * 8;
    float4 f0 = *(const float4*)s;
    float4 f1 = *(const float4*)(s + 4);
    u16x8 v;
    v[0]=f2b(f0.x); v[1]=f2b(f0.y); v[2]=f2b(f0.z); v[3]=f2b(f0.w);
    v[4]=f2b(f1.x); v[5]=f2b(f1.y); v[6]=f2b(f1.z); v[7]=f2b(f1.w);
    *(u16x8*)(dst + ((size_t)(rb * 32 + kb) * 64 + l) * 8) = v;
}

__global__ void init_k(const float* __restrict__ bih, const float* __restrict__ bhh,
                       float* __restrict__ bias) {
    const int i = blockIdx.x * 256 + threadIdx.x;   // 0..4095
    bias[i] = bih[i] + bhh[i];
}

// zero BOTH hrec buffers (tags 0; garbage could alias a future tag).
__global__ void zero_hrec_k(unsigned* __restrict__ hrec) {
    hrec[blockIdx.x * 256 + threadIdx.x] = 0u;      // 2048 dwords
}

// xg[s][n] = sum_k embs[s][k]*W_ih[n][k] + bias[n], bf16 out.
__global__ __launch_bounds__(256, 2)
void gemm_k(const unsigned short* __restrict__ Af, const unsigned short* __restrict__ Bf,
            const float* __restrict__ bias, unsigned short* __restrict__ xg) {
    const int w = threadIdx.x >> 6, l = threadIdx.x & 63;
    const int wid = blockIdx.x * 4 + w;      // 0..4095
    const int mg = wid >> 6;                 // 0..63
    const int ng = wid & 63;                 // 0..63

    f32x4 acc[4][4] = {};
    for (int kb = 0; kb < 32; ++kb) {
        bf16x8 a[4], b[4];
#pragma unroll
        for (int mi = 0; mi < 4; ++mi)
            a[mi] = *(const bf16x8*)(Af + (((size_t)(mg * 4 + mi) * 32 + kb) * 64 + l) * 8);
#pragma unroll
        for (int ni = 0; ni < 4; ++ni)
            b[ni] = *(const bf16x8*)(Bf + (((size_t)(ng * 4 + ni) * 32 + kb) * 64 + l) * 8);
#pragma unroll
        for (int mi = 0; mi < 4; ++mi)
#pragma unroll
            for (int ni = 0; ni < 4; ++ni)
                acc[mi][ni] = __builtin_amdgcn_mfma_f32_16x16x32_bf16(a[mi], b[ni], acc[mi][ni], 0, 0, 0);
    }
    const int r4 = (l >> 4) * 4, c = l & 15;
#pragma unroll
    for (int ni = 0; ni < 4; ++ni) {
        const int col = ng * 64 + ni * 16 + c;
        const float bv = bias[col];
#pragma unroll
        for (int mi = 0; mi < 4; ++mi) {
            const int rowb = mg * 64 + mi * 16 + r4;
#pragma unroll
            for (int i = 0; i < 4; ++i)
                xg[(size_t)(rowb + i) * G4 + col] = f2b(acc[mi][ni][i] + bv);
        }
    }
}

// Persistent LSTM scan. 32 WGs x 512 thr (8 waves). WG r owns h[r*32, r*32+32).
// Wave w: gate w>>1, rows r*32 + (w&1)*16 .. +16 (one 16-row block, 32 MFMAs,
// W_hh in 128 VGPRs -> no spill under launch_bounds(512,2)).
// Transport (r4-proven): 256 dual-tagged 16B chunks at LLC scope (sc0 sc1);
// threads 0..255 poll chunk tid with the drained single-sample loop, with an
// s_sleep(12) phase offset (measured optimal: 6 regressed, batch regressed)
// so sample 1 lands fresh. Waves 4-7 skip polling (wait at B1). Cell redundant
// in all 8 waves; wave w publishes chunk role*8+w. No dangling VMEM anywhere.
__global__ __launch_bounds__(512, 2)
void scan_k(const unsigned short* __restrict__ Wf, const unsigned short* __restrict__ xg,
            unsigned* __restrict__ hrec, float* __restrict__ out) {
    __shared__ unsigned h_sw[512];        // full h as 512 dwords (1024 bf16)
    __shared__ float g_lds[128];          // [gate 0..3][lh 0..31]

    const int role = blockIdx.x;          // 0..31
    const int tid  = threadIdx.x;         // 0..511
    const int w = tid >> 6, l = tid & 63;
    const int gate = w >> 1, half = w & 1;
    const int rb = (gate << 6) + (role << 1) + half;   // row-block index in W packing

    bf16x8 wfrag[32];                     // 128 VGPRs of W_hh (compiler-resident)
#pragma unroll
    for (int kb = 0; kb < 32; ++kb)
        wfrag[kb] = *(const bf16x8*)(Wf + (((size_t)rb * 32 + kb) * 64 + l) * 8);

    float c_reg = 0.f;                    // lanes l<32: cell state (redundant per wave)
    const int hoff = ((l >> 4) & 3) * 8;  // bf16 offset within each 32-chunk of h
    const int r0 = (l >> 4) << 2;
    const unsigned short* h_ss = (const unsigned short*)h_sw;
    const int xbase = (gate << 10) + (role << 5) + (half << 4) + r0;

    // xg t=0 prefetch (plain loads; compiler-managed waits)
    u16x4 xv = {0, 0, 0, 0};
    if ((l & 15) == 0)
        xv = *(const u16x4*)(xg + xbase);

    for (int t = 0; t < Sd; ++t) {
        const unsigned tt = (unsigned)t;

        // ---- waves 0-3: poll own chunk (drained, phase-offset), stage to LDS ----
        if (tid < 256) {
            const unsigned* gp = hrec + (t & 1) * 1024 + tid * 4;
            u32x4 pA;
            __builtin_amdgcn_s_sleep(12);   // ~768cy phase offset (measured optimum)
            int guard = 0;
            while (true) {
                asm volatile("global_load_dwordx4 %0, %1, off sc0 sc1\n\ts_waitcnt vmcnt(0)"
                             : "=v"(pA) : "v"(gp) : "memory");
                __builtin_amdgcn_sched_barrier(0);
                if (!__any((pA[1] != tt) | (pA[3] != tt))) break;
                if (++guard > 65536) break;   // bounded: wrong, never hang
                __builtin_amdgcn_s_sleep(1);
            }
            h_sw[tid * 2]     = pA[0];
            h_sw[tid * 2 + 1] = pA[2];
            asm volatile("s_waitcnt lgkmcnt(0)" ::: "memory");
        }
        __builtin_amdgcn_s_barrier();                          // B1
        __builtin_amdgcn_sched_barrier(0);

        // ---- 32 MFMAs: 4 interleaved 8-deep chains ----
        f32x4 ac0 = {0,0,0,0}, ac1 = {0,0,0,0}, ac2 = {0,0,0,0}, ac3 = {0,0,0,0};
#pragma unroll
        for (int kb = 0; kb < 32; kb += 4) {
            bf16x8 h0 = *(const bf16x8*)(h_ss + (kb + 0) * 32 + hoff);
            bf16x8 h1 = *(const bf16x8*)(h_ss + (kb + 1) * 32 + hoff);
            bf16x8 h2 = *(const bf16x8*)(h_ss + (kb + 2) * 32 + hoff);
            bf16x8 h3 = *(const bf16x8*)(h_ss + (kb + 3) * 32 + hoff);
            ac0 = __builtin_amdgcn_mfma_f32_16x16x32_bf16(wfrag[kb + 0], h0, ac0, 0, 0, 0);
            ac1 = __builtin_amdgcn_mfma_f32_16x16x32_bf16(wfrag[kb + 1], h1, ac1, 0, 0, 0);
            ac2 = __builtin_amdgcn_mfma_f32_16x16x32_bf16(wfrag[kb + 2], h2, ac2, 0, 0, 0);
            ac3 = __builtin_amdgcn_mfma_f32_16x16x32_bf16(wfrag[kb + 3], h3, ac3, 0, 0, 0);
        }
        f32x4 acc = (ac0 + ac1) + (ac2 + ac3);

        if ((l & 15) == 0) {   // lanes 0,16,32,48 hold rows r0..r0+3 (col 0)
#pragma unroll
            for (int i = 0; i < 4; ++i)
                g_lds[(gate << 5) + (half << 4) + r0 + i] = acc[i] + b2f(xv[i]);
        }
        asm volatile("s_waitcnt lgkmcnt(0)" ::: "memory");
        __builtin_amdgcn_s_barrier();                          // B2
        __builtin_amdgcn_sched_barrier(0);

        // ---- LSTM cell, redundant in all 8 waves (lanes l<32) ----
        float h = 0.f; unsigned short hb = 0;
        if (l < 32) {
            float iv = sigmoid_fast(g_lds[l]);
            float fv = sigmoid_fast(g_lds[32 + l]);
            float gv = tanh_fast(g_lds[64 + l]);
            float ov = sigmoid_fast(g_lds[96 + l]);
            float c = fv * c_reg + iv * gv;
            c_reg = c;
            h = ov * tanh_fast(c);
            hb = f2b(h);
        }
        // wave w publishes chunk role*8+w = {h[4w..4w+1], tag, h[4w+2..4w+3], tag}
        unsigned p   = (unsigned)hb | ((unsigned)__shfl_xor((int)(unsigned)hb, 1, 64) << 16);
        unsigned p2v = (unsigned)__shfl((int)p, (l & ~3) + 2, 64);
        if (l == (w << 2)) {
            const unsigned tag = tt + 1u;
            u32x4 val = {p, tag, p2v, tag};
            unsigned* dst = hrec + ((t + 1) & 1) * 1024 + ((role << 3) + w) * 4;
            asm volatile("global_store_dwordx4 %0, %1, off sc0 sc1"
                         :: "v"(dst), "v"(val) : "memory");
        }
        // out[] (wave 0 only) and next-step xg AFTER the publish
        if (w == 0 && l < 32) {
            out[(size_t)Hd + (size_t)t * Hd + (role << 5) + l] = h;   // outs[t]
            if (t == Sd - 1) out[(role << 5) + l] = h;                // final h
        }
        if ((l & 15) == 0)
            xv = *(const u16x4*)(xg + (size_t)(t + 1) * G4 + xbase);
        // per-wave FIFO: the compiler's wait for xv-use (and waves 0-3's poll
        // drains) retire the publish store before the same wave's next publish.
    }
}

extern "C" void kernel_launch(void* const* d_in, const int* in_sizes, int n_in,
                              void* d_out, int out_size, void* d_ws, size_t ws_size,
                              hipStream_t stream) {
    (void)in_sizes; (void)n_in; (void)out_size; (void)ws_size;
    const int*   x   = (const int*)  d_in[0];
    const float* emb = (const float*)d_in[1];
    const float* Wih = (const float*)d_in[2];
    const float* Whh = (const float*)d_in[3];
    const float* bih = (const float*)d_in[4];
    const float* bhh = (const float*)d_in[5];
    float* out = (float*)d_out;

    char* ws = (char*)d_ws;
    unsigned short* whh_f = (unsigned short*)(ws + WS_WHH_F);
    unsigned short* wih_f = (unsigned short*)(ws + WS_WIH_F);
    unsigned short* emb_f = (unsigned short*)(ws + WS_EMB_F);
    unsigned short* xgp   = (unsigned short*)(ws + WS_XG);
    float*          bias  = (float*)        (ws + WS_BIAS);
    unsigned*       hrec  = (unsigned*)      (ws + WS_HREC);

    init_k     <<<16, 256, 0, stream>>>(bih, bhh, bias);
    pack_frag  <<<dim3(256, 32), 64, 0, stream>>>(Whh, nullptr, whh_f);
    pack_frag  <<<dim3(256, 32), 64, 0, stream>>>(Wih, nullptr, wih_f);
    pack_frag  <<<dim3(256, 32), 64, 0, stream>>>(emb, x,       emb_f);
    gemm_k     <<<1024, 256, 0, stream>>>(emb_f, wih_f, bias, xgp);
    zero_hrec_k<<<8, 256, 0, stream>>>(hrec);          // after gemm: hrec aliases emb_f
    scan_k     <<<32, 512, 0, stream>>>(whh_f, xgp, hrec, out);
}